// Round 1
// baseline (92.578 us; speedup 1.0000x reference)
//
#include <hip/hip_runtime.h>
#include <hip/hip_bf16.h>
#include <math.h>

// ---------------------------------------------------------------------------
// Problem: B=32 queries [B,512] vs N=20000 keys [N,512] (fp32).
// scores = Q K^T / sqrt(512); softmax over N; top-8 weights; gather
// values[idx] -> [B*8, 20, 512].  Output = [B*8 weights] ++ [B*8*20*512 vals].
// ---------------------------------------------------------------------------

#define TN 64     // keys per block in scores kernel
#define DC 64     // d-chunk staged in LDS
#define TOPK 8

// Kernel 1: scores[b][n] = dot(q[b], keys[n]) / sqrt(DK)
// block: 256 threads; each block handles TN keys x all 32 queries.
__global__ __launch_bounds__(256) void scores_kernel(
    const float* __restrict__ q, const float* __restrict__ keys,
    float* __restrict__ scores, int N, int B)
{
    const int DK = 512;
    __shared__ float ks[TN][DC + 4];   // +4 pad keeps float4 alignment
    __shared__ float qs[32][DC + 4];

    const int t  = threadIdx.x;
    const int n0 = blockIdx.x * TN;
    const int ng = t & 31;    // thread owns key rows ng, ng+32
    const int bg = t >> 5;    // thread owns query rows bg*4 .. bg*4+3

    float acc[2][4] = {};

    for (int dc = 0; dc < DK; dc += DC) {
        // stage q chunk: 32 x 64 floats = 512 float4, 2 per thread
        #pragma unroll
        for (int i = 0; i < 2; ++i) {
            int idx = t + i * 256;          // 0..511
            int row = idx >> 4;             // 16 float4 per row
            int c4  = idx & 15;
            int r   = row < B ? row : B - 1;
            *reinterpret_cast<float4*>(&qs[row][c4 * 4]) =
                *reinterpret_cast<const float4*>(&q[(size_t)r * DK + dc + c4 * 4]);
        }
        // stage k chunk: 64 x 64 floats = 1024 float4, 4 per thread
        #pragma unroll
        for (int i = 0; i < 4; ++i) {
            int idx = t + i * 256;          // 0..1023
            int row = idx >> 4;
            int c4  = idx & 15;
            int n   = n0 + row;
            if (n >= N) n = N - 1;          // clamp (results discarded on write)
            *reinterpret_cast<float4*>(&ks[row][c4 * 4]) =
                *reinterpret_cast<const float4*>(&keys[(size_t)n * DK + dc + c4 * 4]);
        }
        __syncthreads();

        #pragma unroll
        for (int d4 = 0; d4 < DC / 4; ++d4) {
            float4 kv0 = *reinterpret_cast<const float4*>(&ks[ng][d4 * 4]);
            float4 kv1 = *reinterpret_cast<const float4*>(&ks[ng + 32][d4 * 4]);
            float4 qv[4];
            #pragma unroll
            for (int j = 0; j < 4; ++j)
                qv[j] = *reinterpret_cast<const float4*>(&qs[bg * 4 + j][d4 * 4]);
            #pragma unroll
            for (int j = 0; j < 4; ++j) {
                acc[0][j] += kv0.x * qv[j].x + kv0.y * qv[j].y +
                             kv0.z * qv[j].z + kv0.w * qv[j].w;
                acc[1][j] += kv1.x * qv[j].x + kv1.y * qv[j].y +
                             kv1.z * qv[j].z + kv1.w * qv[j].w;
            }
        }
        __syncthreads();
    }

    const float scale = 1.0f / sqrtf((float)DK);
    #pragma unroll
    for (int i = 0; i < 2; ++i) {
        int n = n0 + ng + 32 * i;
        if (n < N) {
            #pragma unroll
            for (int j = 0; j < 4; ++j)
                scores[(size_t)(bg * 4 + j) * N + n] = acc[i][j] * scale;
        }
    }
}

// Kernel 2: per row b: global max, sum(exp(s-max)), top-8 (lax.top_k order:
// descending value, smaller index first on ties). One block per row.
__global__ __launch_bounds__(256) void topk_kernel(
    const float* __restrict__ scores, float* __restrict__ out_w,
    int* __restrict__ out_idx, int N)
{
    const int b = blockIdx.x;
    const int t = threadIdx.x;
    const float* row = scores + (size_t)b * N;

    __shared__ float red[256];
    __shared__ float cval[256 * TOPK];
    __shared__ int   cidx[256 * TOPK];
    __shared__ float hv[256];
    __shared__ int   hidx[256];
    __shared__ int   howner[256];
    __shared__ float rv_s[TOPK];
    __shared__ int   ri_s[TOPK];

    const int n4 = N >> 2;

    // ---- pass 1: row max ----
    float m = -INFINITY;
    for (int i = t; i < n4; i += 256) {
        float4 v = reinterpret_cast<const float4*>(row)[i];
        m = fmaxf(m, fmaxf(fmaxf(v.x, v.y), fmaxf(v.z, v.w)));
    }
    for (int i = 4 * n4 + t; i < N; i += 256) m = fmaxf(m, row[i]);
    red[t] = m; __syncthreads();
    for (int s = 128; s > 0; s >>= 1) {
        if (t < s) red[t] = fmaxf(red[t], red[t + s]);
        __syncthreads();
    }
    m = red[0];
    __syncthreads();

    // ---- pass 2: sum(exp) + per-thread top-8 ----
    float* tv = &cval[t * TOPK];
    int*   ti = &cidx[t * TOPK];
    #pragma unroll
    for (int j = 0; j < TOPK; ++j) { tv[j] = -INFINITY; ti[j] = 0x7fffffff; }

    float sum = 0.0f;
    for (int i = t; i < n4; i += 256) {
        float4 v = reinterpret_cast<const float4*>(row)[i];
        float vv[4] = {v.x, v.y, v.z, v.w};
        #pragma unroll
        for (int c = 0; c < 4; ++c) {
            float x = vv[c];
            sum += __expf(x - m);
            if (x > tv[TOPK - 1]) {     // strict > keeps earlier (smaller) index on ties
                int j = TOPK - 1;
                while (j > 0 && tv[j - 1] < x) {
                    tv[j] = tv[j - 1]; ti[j] = ti[j - 1]; --j;
                }
                tv[j] = x; ti[j] = 4 * i + c;
            }
        }
    }
    for (int i = 4 * n4 + t; i < N; i += 256) {
        float x = row[i];
        sum += __expf(x - m);
        if (x > tv[TOPK - 1]) {
            int j = TOPK - 1;
            while (j > 0 && tv[j - 1] < x) {
                tv[j] = tv[j - 1]; ti[j] = ti[j - 1]; --j;
            }
            tv[j] = x; ti[j] = i;
        }
    }
    red[t] = sum; __syncthreads();
    for (int s = 128; s > 0; s >>= 1) {
        if (t < s) red[t] += red[t + s];
        __syncthreads();
    }
    const float denom = red[0];
    __syncthreads();

    // ---- merge 256 sorted lists: 8 selection rounds ----
    int head = 0;
    for (int r = 0; r < TOPK; ++r) {
        hv[t]     = (head < TOPK) ? tv[head] : -INFINITY;
        hidx[t]   = (head < TOPK) ? ti[head] : 0x7fffffff;
        howner[t] = t;
        __syncthreads();
        for (int s = 128; s > 0; s >>= 1) {
            if (t < s) {
                float v2 = hv[t + s]; int i2 = hidx[t + s];
                if (v2 > hv[t] || (v2 == hv[t] && i2 < hidx[t])) {
                    hv[t] = v2; hidx[t] = i2; howner[t] = howner[t + s];
                }
            }
            __syncthreads();
        }
        if (t == 0) { rv_s[r] = hv[0]; ri_s[r] = hidx[0]; }
        int win = howner[0];
        if (t == win) ++head;
        __syncthreads();
    }

    if (t < TOPK) {
        out_w[b * TOPK + t]   = __expf(rv_s[t] - m) / denom;
        out_idx[b * TOPK + t] = ri_s[t];
    }
}

// Kernel 3: gather values[idx] -> out.  One block per (b,k) pair.
__global__ __launch_bounds__(256) void gather_kernel(
    const float* __restrict__ values, const int* __restrict__ idx,
    float* __restrict__ out, int LDV)
{
    const int bk = blockIdx.x;
    const int id = idx[bk];
    const float4* src = reinterpret_cast<const float4*>(values + (size_t)id * LDV);
    float4*       dst = reinterpret_cast<float4*>(out + (size_t)bk * LDV);
    const int n4 = LDV >> 2;
    for (int i = threadIdx.x; i < n4; i += 256) dst[i] = src[i];
}

extern "C" void kernel_launch(void* const* d_in, const int* in_sizes, int n_in,
                              void* d_out, int out_size, void* d_ws, size_t ws_size,
                              hipStream_t stream) {
    const float* q      = (const float*)d_in[0];
    const float* keys   = (const float*)d_in[1];
    const float* values = (const float*)d_in[2];

    const int DK  = 512;
    const int B   = in_sizes[0] / DK;        // 32
    const int N   = in_sizes[1] / DK;        // 20000
    const int LDV = (int)((long long)in_sizes[2] / N);  // L*DV = 10240

    float* out   = (float*)d_out;
    float* out_w = out;                       // [B*8]
    float* out_v = out + (size_t)B * TOPK;    // [B*8, L*DV]

    float* scores = (float*)d_ws;                                    // B*N floats
    int*   tidx   = (int*)((char*)d_ws + (size_t)B * N * sizeof(float)); // B*8 ints

    scores_kernel<<<(N + TN - 1) / TN, 256, 0, stream>>>(q, keys, scores, N, B);
    topk_kernel<<<B, 256, 0, stream>>>(scores, out_w, tidx, N);
    gather_kernel<<<B * TOPK, 256, 0, stream>>>(values, tidx, out_v, LDV);
}

// Round 2
// 59.501 us; speedup vs baseline: 1.5559x; 1.5559x over previous
//
#include <hip/hip_runtime.h>
#include <math.h>

// ---------------------------------------------------------------------------
// B=32 queries [B,512] fp32 vs N=20000 keys [N,512] fp32.
// scores = Q K^T / sqrt(512); softmax over N; top-8; gather values rows.
// Output = [B*8 weights f32] ++ [B*8 * 10240 values f32].
//
// Pipeline:
//  K0 qsplit:   q -> bf16 hi/lo pair (ws)                       ~1 us
//  K1 scores:   3-pass bf16 MFMA (qh*kh + ql*kh + qh*kl), keys
//               streamed global->reg, 1250 one-wave blocks      ~7-9 us (HBM)
//  K2a part:    32x8 chunk blocks: online max/sum-exp + top-8   ~2-3 us
//  K2b final:   per row: merge 64 cands, EXACT fp32 rescore of
//               top-12, exact sort, weights                     ~2 us
//  K3 gather:   512 blocks copy 40KB rows                       ~5-6 us
// ---------------------------------------------------------------------------

#define TOPK 8
#define BQ 32
#define DKD 512
#define NCHUNK 8

typedef __attribute__((ext_vector_type(8))) short short8;
typedef __attribute__((ext_vector_type(4))) float f32x4;

__device__ inline unsigned short f2bf(float x) {
    unsigned int u = __float_as_uint(x);
    u = (u + 0x7fffu + ((u >> 16) & 1u)) >> 16;   // RNE to bf16
    return (unsigned short)u;
}
__device__ inline float bf2f(unsigned short h) {
    return __uint_as_float(((unsigned int)h) << 16);
}

// comparator everywhere: value desc, index asc (matches lax.top_k ties)
__device__ inline void wave_argmax(float& v, int& i) {
    #pragma unroll
    for (int off = 1; off < 64; off <<= 1) {
        float ov = __shfl_xor(v, off);
        int   oi = __shfl_xor(i, off);
        if (ov > v || (ov == v && oi < i)) { v = ov; i = oi; }
    }
}

// ---- K0: split q into bf16 hi/lo ------------------------------------------
__global__ __launch_bounds__(128) void qsplit_kernel(
    const float* __restrict__ q, unsigned short* __restrict__ qh,
    unsigned short* __restrict__ ql)
{
    const int row = blockIdx.x;            // 32 rows
    const int t = threadIdx.x;             // 128 thr x 4 floats
    float4 v = *reinterpret_cast<const float4*>(&q[row * DKD + t * 4]);
    float xs[4] = {v.x, v.y, v.z, v.w};
    ushort4 ho, lo;
    unsigned short* hp = &ho.x;
    unsigned short* lp = &lo.x;
    #pragma unroll
    for (int e = 0; e < 4; ++e) {
        unsigned short hb = f2bf(xs[e]);
        hp[e] = hb;
        lp[e] = f2bf(xs[e] - bf2f(hb));
    }
    *reinterpret_cast<ushort4*>(&qh[row * DKD + t * 4]) = ho;
    *reinterpret_cast<ushort4*>(&ql[row * DKD + t * 4]) = lo;
}

// ---- K1: scores via 3-pass bf16-split MFMA --------------------------------
// One wave per block; block handles 16 keys x all 32 queries x K=512.
__global__ __launch_bounds__(64) void scores_mfma_kernel(
    const float* __restrict__ keys, const unsigned short* __restrict__ qh,
    const unsigned short* __restrict__ ql, float* __restrict__ scores, int N)
{
    const int lane = threadIdx.x;
    const int n0   = blockIdx.x * 16;
    const int col  = lane & 15;            // key within tile / q-row in frags
    const int kg   = lane >> 4;            // k-chunk group 0..3
    const float scale = 0.04419417382415922f; // 1/sqrt(512)

    f32x4 acc0 = {0.f, 0.f, 0.f, 0.f};
    f32x4 acc1 = {0.f, 0.f, 0.f, 0.f};

    const float*          krow = keys + (size_t)(n0 + col) * DKD + kg * 8;
    const unsigned short* q0h  = qh + (size_t)col * DKD + kg * 8;
    const unsigned short* q0l  = ql + (size_t)col * DKD + kg * 8;
    const unsigned short* q1h  = qh + (size_t)(col + 16) * DKD + kg * 8;
    const unsigned short* q1l  = ql + (size_t)(col + 16) * DKD + kg * 8;

    #pragma unroll 4
    for (int ks = 0; ks < 16; ++ks) {
        const int d = ks * 32;
        float4 ka = *reinterpret_cast<const float4*>(krow + d);
        float4 kb = *reinterpret_cast<const float4*>(krow + d + 4);
        float kv[8] = {ka.x, ka.y, ka.z, ka.w, kb.x, kb.y, kb.z, kb.w};
        short8 fh, fl;
        #pragma unroll
        for (int e = 0; e < 8; ++e) {
            unsigned short hb = f2bf(kv[e]);
            fh[e] = (short)hb;
            fl[e] = (short)f2bf(kv[e] - bf2f(hb));
        }
        short8 a0h = *reinterpret_cast<const short8*>(q0h + d);
        short8 a0l = *reinterpret_cast<const short8*>(q0l + d);
        short8 a1h = *reinterpret_cast<const short8*>(q1h + d);
        short8 a1l = *reinterpret_cast<const short8*>(q1l + d);

        acc0 = __builtin_amdgcn_mfma_f32_16x16x32_bf16(a0h, fh, acc0, 0, 0, 0);
        acc0 = __builtin_amdgcn_mfma_f32_16x16x32_bf16(a0l, fh, acc0, 0, 0, 0);
        acc0 = __builtin_amdgcn_mfma_f32_16x16x32_bf16(a0h, fl, acc0, 0, 0, 0);
        acc1 = __builtin_amdgcn_mfma_f32_16x16x32_bf16(a1h, fh, acc1, 0, 0, 0);
        acc1 = __builtin_amdgcn_mfma_f32_16x16x32_bf16(a1l, fh, acc1, 0, 0, 0);
        acc1 = __builtin_amdgcn_mfma_f32_16x16x32_bf16(a1h, fl, acc1, 0, 0, 0);
    }

    // D layout (m89-verified): col = lane&15, row = (lane>>4)*4 + reg
    #pragma unroll
    for (int j = 0; j < 4; ++j) {
        const int r = kg * 4 + j;
        scores[(size_t)r * N + n0 + col]        = acc0[j] * scale;
        scores[(size_t)(r + 16) * N + n0 + col] = acc1[j] * scale;
    }
}

// ---- K2a: per (row, chunk): online max + sum(exp) + top-8 -----------------
__global__ __launch_bounds__(256) void part_kernel(
    const float* __restrict__ scores, float* __restrict__ pm,
    float* __restrict__ ps, float* __restrict__ cv, int* __restrict__ ci,
    int N, int chunk)
{
    const int bid = blockIdx.x;            // b*NCHUNK + c
    const int b = bid >> 3, c = bid & 7;
    const int t = threadIdx.x;
    const int ln = t & 63, w = t >> 6;
    const float* base = scores + (size_t)b * N + c * chunk;
    const int i0 = c * chunk;
    const int n4 = chunk >> 2;             // 625

    float m = -INFINITY, s = 0.0f;
    float v[TOPK];
    int   j[TOPK];
    #pragma unroll
    for (int k = 0; k < TOPK; ++k) { v[k] = -INFINITY; j[k] = 0x7fffffff; }

    for (int i = t; i < n4; i += 256) {
        float4 x4 = reinterpret_cast<const float4*>(base)[i];
        float xs[4] = {x4.x, x4.y, x4.z, x4.w};
        #pragma unroll
        for (int e = 0; e < 4; ++e) {
            const float x = xs[e];
            const int  gi = i0 + i * 4 + e;
            const float nm = fmaxf(m, x);
            s = s * __expf(m - nm) + __expf(x - nm);
            m = nm;
            if (x > v[TOPK - 1]) {
                bool g[TOPK];
                #pragma unroll
                for (int k = 0; k < TOPK; ++k) g[k] = (x > v[k]);
                #pragma unroll
                for (int k = TOPK - 1; k >= 1; --k) {
                    v[k] = g[k] ? (g[k - 1] ? v[k - 1] : x) : v[k];
                    j[k] = g[k] ? (g[k - 1] ? j[k - 1] : gi) : j[k];
                }
                v[0] = g[0] ? x : v[0];
                j[0] = g[0] ? gi : j[0];
            }
        }
    }

    // wave-level (m,s) combine
    #pragma unroll
    for (int off = 1; off < 64; off <<= 1) {
        float om = __shfl_xor(m, off), os = __shfl_xor(s, off);
        float M2 = fmaxf(m, om);
        s = s * __expf(m - M2) + os * __expf(om - M2);
        m = M2;
    }

    // wave-level top-8 merge: 8 selection rounds over lanes' sorted lists
    float selv = 0.f; int seli = 0;
    #pragma unroll
    for (int r = 0; r < TOPK; ++r) {
        float mv = v[0]; int mi = j[0];
        wave_argmax(mv, mi);
        if (v[0] == mv && j[0] == mi) {        // I won: pop my head
            #pragma unroll
            for (int k = 0; k < TOPK - 1; ++k) { v[k] = v[k + 1]; j[k] = j[k + 1]; }
            v[TOPK - 1] = -INFINITY; j[TOPK - 1] = 0x7fffffff;
        }
        if (ln == r) { selv = mv; seli = mi; }
    }

    __shared__ float lm[4], ls[4], lcv[4][TOPK];
    __shared__ int   lci[4][TOPK];
    if (ln == 0) { lm[w] = m; ls[w] = s; }
    if (ln < TOPK) { lcv[w][ln] = selv; lci[w][ln] = seli; }
    __syncthreads();

    if (w == 0) {
        if (ln == 0) {
            float M = lm[0], S = ls[0];
            #pragma unroll
            for (int cc = 1; cc < 4; ++cc) {
                float M2 = fmaxf(M, lm[cc]);
                S = S * __expf(M - M2) + ls[cc] * __expf(lm[cc] - M2);
                M = M2;
            }
            pm[bid] = M; ps[bid] = S;
        }
        float vv = (ln < 32) ? lcv[ln >> 3][ln & 7] : -INFINITY;
        int   ii = (ln < 32) ? lci[ln >> 3][ln & 7] : 0x7fffffff;
        #pragma unroll
        for (int r = 0; r < TOPK; ++r) {
            float mv = vv; int mi = ii;
            wave_argmax(mv, mi);
            if (vv == mv && ii == mi) vv = -INFINITY;
            if (ln == r) { cv[bid * TOPK + r] = mv; ci[bid * TOPK + r] = mi; }
        }
    }
}

// ---- K2b: per row: denom, merge 64 cands, exact rescore top-12, weights ---
__global__ __launch_bounds__(64) void final_kernel(
    const float* __restrict__ q, const float* __restrict__ keys,
    const float* __restrict__ pm, const float* __restrict__ ps,
    const float* __restrict__ cv, const int* __restrict__ ci,
    float* __restrict__ out_w, int* __restrict__ tidx)
{
    const int b = blockIdx.x;
    const int ln = threadIdx.x;
    const float scale = 0.04419417382415922f;

    float M = -INFINITY;
    #pragma unroll
    for (int c = 0; c < NCHUNK; ++c) M = fmaxf(M, pm[b * NCHUNK + c]);
    float S = 0.f;
    #pragma unroll
    for (int c = 0; c < NCHUNK; ++c)
        S += ps[b * NCHUNK + c] * __expf(pm[b * NCHUNK + c] - M);

    // 64 candidates, select approx top-12
    float vv = cv[b * 64 + ln];
    int   ii = ci[b * 64 + ln];
    float sv = -INFINITY; int si = 0x7fffffff;
    #pragma unroll
    for (int r = 0; r < 12; ++r) {
        float mv = vv; int mi = ii;
        wave_argmax(mv, mi);
        if (vv == mv && ii == mi) vv = -INFINITY;
        if (ln == r) { sv = mv; si = mi; }
    }

    // exact fp32 rescore of the 12 candidates
    float4 qa = *reinterpret_cast<const float4*>(q + (size_t)b * DKD + ln * 8);
    float4 qb = *reinterpret_cast<const float4*>(q + (size_t)b * DKD + ln * 8 + 4);
    float exv = -INFINITY;
    #pragma unroll
    for (int r = 0; r < 12; ++r) {
        const int cand = __shfl(si, r);
        const float* kr = keys + (size_t)cand * DKD + ln * 8;
        float4 k1 = *reinterpret_cast<const float4*>(kr);
        float4 k2 = *reinterpret_cast<const float4*>(kr + 4);
        float p = qa.x * k1.x + qa.y * k1.y + qa.z * k1.z + qa.w * k1.w
                + qb.x * k2.x + qb.y * k2.y + qb.z * k2.z + qb.w * k2.w;
        #pragma unroll
        for (int off = 1; off < 64; off <<= 1) p += __shfl_xor(p, off);
        if (ln == r) exv = p * scale;
    }

    // exact top-8 of 12, emit weights (max M cancels num/denom)
    float fv = (ln < 12) ? exv : -INFINITY;
    int   fi = (ln < 12) ? si : 0x7fffffff;
    #pragma unroll
    for (int r = 0; r < TOPK; ++r) {
        float mv = fv; int mi = fi;
        wave_argmax(mv, mi);
        if (fv == mv && fi == mi) fv = -INFINITY;
        if (ln == r) {
            out_w[b * TOPK + r] = __expf(mv - M) / S;
            tidx[b * TOPK + r]  = mi;
        }
    }
}

// ---- K3: gather values rows ------------------------------------------------
__global__ __launch_bounds__(256) void gather_kernel(
    const float* __restrict__ values, const int* __restrict__ idx,
    float* __restrict__ out, int LDV)
{
    const int bk = blockIdx.x >> 1;
    const int half = blockIdx.x & 1;
    const int id = idx[bk];
    const float4* src = reinterpret_cast<const float4*>(values + (size_t)id * LDV);
    float4*       dst = reinterpret_cast<float4*>(out + (size_t)bk * LDV);
    const int n4 = LDV >> 2;                 // 2560
    const int hn = n4 >> 1;                  // 1280
    for (int i = half * hn + threadIdx.x; i < (half + 1) * hn; i += 256)
        dst[i] = src[i];
}

extern "C" void kernel_launch(void* const* d_in, const int* in_sizes, int n_in,
                              void* d_out, int out_size, void* d_ws, size_t ws_size,
                              hipStream_t stream) {
    const float* q      = (const float*)d_in[0];
    const float* keys   = (const float*)d_in[1];
    const float* values = (const float*)d_in[2];

    const int B   = in_sizes[0] / DKD;                 // 32
    const int N   = in_sizes[1] / DKD;                 // 20000
    const int LDV = (int)((long long)in_sizes[2] / N); // 10240
    const int chunk = N / NCHUNK;                      // 2500

    float* out   = (float*)d_out;
    float* out_w = out;
    float* out_v = out + (size_t)B * TOPK;

    char* wsb = (char*)d_ws;
    size_t off = 0;
    float* scores = (float*)(wsb + off); off += (size_t)B * N * sizeof(float);
    unsigned short* qh = (unsigned short*)(wsb + off); off += (size_t)B * DKD * 2;
    unsigned short* ql = (unsigned short*)(wsb + off); off += (size_t)B * DKD * 2;
    float* pm = (float*)(wsb + off); off += (size_t)B * NCHUNK * sizeof(float);
    float* ps = (float*)(wsb + off); off += (size_t)B * NCHUNK * sizeof(float);
    float* cv = (float*)(wsb + off); off += (size_t)B * NCHUNK * TOPK * sizeof(float);
    int*   ci = (int*)(wsb + off);   off += (size_t)B * NCHUNK * TOPK * sizeof(int);
    int*   tidx = (int*)(wsb + off); off += (size_t)B * TOPK * sizeof(int);

    qsplit_kernel<<<B, 128, 0, stream>>>(q, qh, ql);
    scores_mfma_kernel<<<N / 16, 64, 0, stream>>>(keys, qh, ql, scores, N);
    part_kernel<<<B * NCHUNK, 256, 0, stream>>>(scores, pm, ps, cv, ci, N, chunk);
    final_kernel<<<B, 64, 0, stream>>>(q, keys, pm, ps, cv, ci, out_w, tidx);
    gather_kernel<<<B * TOPK * 2, 256, 0, stream>>>(values, tidx, out_v, LDV);
}

// Round 3
// 58.972 us; speedup vs baseline: 1.5699x; 1.0090x over previous
//
#include <hip/hip_runtime.h>
#include <math.h>

// ---------------------------------------------------------------------------
// B=32 queries [B,512] fp32 vs N=20000 keys [N,512] fp32.
// scores = Q K^T / sqrt(512); softmax over N; top-8; gather values rows.
// Output = [B*8 weights f32] ++ [B*8 * 10240 values f32].
//
// Architecture: approx bf16 MFMA scores (sigma ~3e-3, only used to SELECT
// top-12 candidates + softmax denom) -> exact fp32 rescore of candidates ->
// exact ordering/indices, weights err ~1e-3 << 0.1 threshold.
//  K0 qsplit:  q -> bf16 RNE                                   (32 blk)
//  K1 scores:  1-term bf16 MFMA, 16 keys/wave, 4 waves/block   (313 blk)
//  K2a part:   per (row,chunk) online max/sum-exp + top-8      (256 blk)
//  K2b final:  merge 64 cands, exact rescore top-12, weights   (32 blk)
//  K3 gather:  values[idx] rows, 4 blocks/row                  (1024 blk)
// ---------------------------------------------------------------------------

#define TOPK 8
#define DKD 512
#define NCHUNK 8

typedef __attribute__((ext_vector_type(8))) short short8;
typedef __attribute__((ext_vector_type(4))) float f32x4;

__device__ inline unsigned short f2bf(float x) {
    unsigned int u = __float_as_uint(x);
    u = (u + 0x7fffu + ((u >> 16) & 1u)) >> 16;   // RNE to bf16
    return (unsigned short)u;
}

// comparator everywhere: value desc, index asc (matches lax.top_k ties)
__device__ inline void wave_argmax(float& v, int& i) {
    #pragma unroll
    for (int off = 1; off < 64; off <<= 1) {
        float ov = __shfl_xor(v, off);
        int   oi = __shfl_xor(i, off);
        if (ov > v || (ov == v && oi < i)) { v = ov; i = oi; }
    }
}

// ---- K0: q -> bf16 (RNE) ---------------------------------------------------
__global__ __launch_bounds__(128) void qsplit_kernel(
    const float* __restrict__ q, unsigned short* __restrict__ qh)
{
    const int row = blockIdx.x;            // 32 rows
    const int t = threadIdx.x;             // 128 thr x 4 floats
    float4 v = *reinterpret_cast<const float4*>(&q[row * DKD + t * 4]);
    ushort4 h;
    h.x = f2bf(v.x); h.y = f2bf(v.y); h.z = f2bf(v.z); h.w = f2bf(v.w);
    *reinterpret_cast<ushort4*>(&qh[row * DKD + t * 4]) = h;
}

// ---- K1: approx scores via single bf16 MFMA --------------------------------
// 4 waves/block; each wave: 16 keys x 32 queries x K=512.
__global__ __launch_bounds__(256) void scores_mfma_kernel(
    const float* __restrict__ keys, const unsigned short* __restrict__ qh,
    float* __restrict__ scores, int N)
{
    const int lane = threadIdx.x & 63;
    const int wid  = threadIdx.x >> 6;
    const int n0   = blockIdx.x * 64 + wid * 16;
    const int col  = lane & 15;            // key within tile / q-row in frags
    const int kg   = lane >> 4;            // k-chunk group 0..3
    const float scale = 0.04419417382415922f; // 1/sqrt(512)

    f32x4 acc0 = {0.f, 0.f, 0.f, 0.f};
    f32x4 acc1 = {0.f, 0.f, 0.f, 0.f};

    int nrow = n0 + col;
    const bool valid = (nrow < N);
    if (!valid) nrow = N - 1;              // clamp loads, skip stores
    const float*          krow = keys + (size_t)nrow * DKD + kg * 8;
    const unsigned short* q0   = qh + (size_t)col * DKD + kg * 8;
    const unsigned short* q1   = qh + (size_t)(col + 16) * DKD + kg * 8;

    #pragma unroll 4
    for (int ks = 0; ks < 16; ++ks) {
        const int d = ks * 32;
        float4 ka = *reinterpret_cast<const float4*>(krow + d);
        float4 kb = *reinterpret_cast<const float4*>(krow + d + 4);
        short8 fh;
        fh[0] = (short)f2bf(ka.x); fh[1] = (short)f2bf(ka.y);
        fh[2] = (short)f2bf(ka.z); fh[3] = (short)f2bf(ka.w);
        fh[4] = (short)f2bf(kb.x); fh[5] = (short)f2bf(kb.y);
        fh[6] = (short)f2bf(kb.z); fh[7] = (short)f2bf(kb.w);
        short8 a0 = *reinterpret_cast<const short8*>(q0 + d);
        short8 a1 = *reinterpret_cast<const short8*>(q1 + d);
        acc0 = __builtin_amdgcn_mfma_f32_16x16x32_bf16(a0, fh, acc0, 0, 0, 0);
        acc1 = __builtin_amdgcn_mfma_f32_16x16x32_bf16(a1, fh, acc1, 0, 0, 0);
    }

    // D layout (m89-verified): col = lane&15, row = (lane>>4)*4 + reg
    if (valid) {
        #pragma unroll
        for (int j = 0; j < 4; ++j) {
            const int r = kg * 4 + j;
            scores[(size_t)r * N + n0 + col]        = acc0[j] * scale;
            scores[(size_t)(r + 16) * N + n0 + col] = acc1[j] * scale;
        }
    }
}

// ---- K2a: per (row, chunk): online max + sum(exp) + top-8 -----------------
__global__ __launch_bounds__(256) void part_kernel(
    const float* __restrict__ scores, float* __restrict__ pm,
    float* __restrict__ ps, float* __restrict__ cv, int* __restrict__ ci,
    int N, int chunk)
{
    const int bid = blockIdx.x;            // b*NCHUNK + c
    const int b = bid >> 3, c = bid & 7;
    const int t = threadIdx.x;
    const int ln = t & 63, w = t >> 6;
    const float* base = scores + (size_t)b * N + c * chunk;
    const int i0 = c * chunk;
    const int n4 = chunk >> 2;             // 625

    float m = -INFINITY, s = 0.0f;
    float v[TOPK];
    int   j[TOPK];
    #pragma unroll
    for (int k = 0; k < TOPK; ++k) { v[k] = -INFINITY; j[k] = 0x7fffffff; }

    for (int i = t; i < n4; i += 256) {
        float4 x4 = reinterpret_cast<const float4*>(base)[i];
        float xs[4] = {x4.x, x4.y, x4.z, x4.w};
        #pragma unroll
        for (int e = 0; e < 4; ++e) {
            const float x = xs[e];
            const int  gi = i0 + i * 4 + e;
            const float nm = fmaxf(m, x);
            s = s * __expf(m - nm) + __expf(x - nm);
            m = nm;
            if (x > v[TOPK - 1]) {
                bool g[TOPK];
                #pragma unroll
                for (int k = 0; k < TOPK; ++k) g[k] = (x > v[k]);
                #pragma unroll
                for (int k = TOPK - 1; k >= 1; --k) {
                    v[k] = g[k] ? (g[k - 1] ? v[k - 1] : x) : v[k];
                    j[k] = g[k] ? (g[k - 1] ? j[k - 1] : gi) : j[k];
                }
                v[0] = g[0] ? x : v[0];
                j[0] = g[0] ? gi : j[0];
            }
        }
    }

    // wave-level (m,s) combine
    #pragma unroll
    for (int off = 1; off < 64; off <<= 1) {
        float om = __shfl_xor(m, off), os = __shfl_xor(s, off);
        float M2 = fmaxf(m, om);
        s = s * __expf(m - M2) + os * __expf(om - M2);
        m = M2;
    }

    // wave-level top-8 merge: 8 selection rounds over lanes' sorted lists
    float selv = 0.f; int seli = 0;
    #pragma unroll
    for (int r = 0; r < TOPK; ++r) {
        float mv = v[0]; int mi = j[0];
        wave_argmax(mv, mi);
        if (v[0] == mv && j[0] == mi) {        // I won: pop my head
            #pragma unroll
            for (int k = 0; k < TOPK - 1; ++k) { v[k] = v[k + 1]; j[k] = j[k + 1]; }
            v[TOPK - 1] = -INFINITY; j[TOPK - 1] = 0x7fffffff;
        }
        if (ln == r) { selv = mv; seli = mi; }
    }

    __shared__ float lm[4], ls[4], lcv[4][TOPK];
    __shared__ int   lci[4][TOPK];
    if (ln == 0) { lm[w] = m; ls[w] = s; }
    if (ln < TOPK) { lcv[w][ln] = selv; lci[w][ln] = seli; }
    __syncthreads();

    if (w == 0) {
        if (ln == 0) {
            float M = lm[0], S = ls[0];
            #pragma unroll
            for (int cc = 1; cc < 4; ++cc) {
                float M2 = fmaxf(M, lm[cc]);
                S = S * __expf(M - M2) + ls[cc] * __expf(lm[cc] - M2);
                M = M2;
            }
            pm[bid] = M; ps[bid] = S;
        }
        float vv = (ln < 32) ? lcv[ln >> 3][ln & 7] : -INFINITY;
        int   ii = (ln < 32) ? lci[ln >> 3][ln & 7] : 0x7fffffff;
        #pragma unroll
        for (int r = 0; r < TOPK; ++r) {
            float mv = vv; int mi = ii;
            wave_argmax(mv, mi);
            if (vv == mv && ii == mi) vv = -INFINITY;
            if (ln == r) { cv[bid * TOPK + r] = mv; ci[bid * TOPK + r] = mi; }
        }
    }
}

// ---- K2b: per row: denom, merge 64 cands, exact rescore top-12, weights ---
__global__ __launch_bounds__(64) void final_kernel(
    const float* __restrict__ q, const float* __restrict__ keys,
    const float* __restrict__ pm, const float* __restrict__ ps,
    const float* __restrict__ cv, const int* __restrict__ ci,
    float* __restrict__ out_w, int* __restrict__ tidx)
{
    const int b = blockIdx.x;
    const int ln = threadIdx.x;
    const float scale = 0.04419417382415922f;

    float M = -INFINITY;
    #pragma unroll
    for (int c = 0; c < NCHUNK; ++c) M = fmaxf(M, pm[b * NCHUNK + c]);
    float S = 0.f;
    #pragma unroll
    for (int c = 0; c < NCHUNK; ++c)
        S += ps[b * NCHUNK + c] * __expf(pm[b * NCHUNK + c] - M);

    // 64 candidates, select approx top-12
    float vv = cv[b * 64 + ln];
    int   ii = ci[b * 64 + ln];
    int si = 0x7fffffff;
    #pragma unroll
    for (int r = 0; r < 12; ++r) {
        float mv = vv; int mi = ii;
        wave_argmax(mv, mi);
        if (vv == mv && ii == mi) vv = -INFINITY;
        if (ln == r) si = mi;
    }

    // exact fp32 rescore of the 12 candidates
    float4 qa = *reinterpret_cast<const float4*>(q + (size_t)b * DKD + ln * 8);
    float4 qb = *reinterpret_cast<const float4*>(q + (size_t)b * DKD + ln * 8 + 4);
    float exv = -INFINITY;
    #pragma unroll
    for (int r = 0; r < 12; ++r) {
        const int cand = __shfl(si, r);
        const float* kr = keys + (size_t)cand * DKD + ln * 8;
        float4 k1 = *reinterpret_cast<const float4*>(kr);
        float4 k2 = *reinterpret_cast<const float4*>(kr + 4);
        float p = qa.x * k1.x + qa.y * k1.y + qa.z * k1.z + qa.w * k1.w
                + qb.x * k2.x + qb.y * k2.y + qb.z * k2.z + qb.w * k2.w;
        #pragma unroll
        for (int off = 1; off < 64; off <<= 1) p += __shfl_xor(p, off);
        if (ln == r) exv = p * scale;
    }

    // exact top-8 of 12, emit weights (max M cancels num/denom)
    float fv = (ln < 12) ? exv : -INFINITY;
    int   fi = (ln < 12) ? si : 0x7fffffff;
    #pragma unroll
    for (int r = 0; r < TOPK; ++r) {
        float mv = fv; int mi = fi;
        wave_argmax(mv, mi);
        if (fv == mv && fi == mi) fv = -INFINITY;
        if (ln == r) {
            out_w[b * TOPK + r] = __expf(mv - M) / S;
            tidx[b * TOPK + r]  = mi;
        }
    }
}

// ---- K3: gather values rows (4 blocks per output row) ---------------------
__global__ __launch_bounds__(256) void gather_kernel(
    const float* __restrict__ values, const int* __restrict__ idx,
    float* __restrict__ out, int LDV)
{
    const int bk  = blockIdx.x >> 2;
    const int qtr = blockIdx.x & 3;
    const int id = idx[bk];
    const float4* src = reinterpret_cast<const float4*>(values + (size_t)id * LDV);
    float4*       dst = reinterpret_cast<float4*>(out + (size_t)bk * LDV);
    const int n4 = LDV >> 2;                 // 2560
    const int qn = n4 >> 2;                  // 640
    for (int i = qtr * qn + threadIdx.x; i < (qtr + 1) * qn; i += 256)
        dst[i] = src[i];
}

extern "C" void kernel_launch(void* const* d_in, const int* in_sizes, int n_in,
                              void* d_out, int out_size, void* d_ws, size_t ws_size,
                              hipStream_t stream) {
    const float* q      = (const float*)d_in[0];
    const float* keys   = (const float*)d_in[1];
    const float* values = (const float*)d_in[2];

    const int B   = in_sizes[0] / DKD;                 // 32
    const int N   = in_sizes[1] / DKD;                 // 20000
    const int LDV = (int)((long long)in_sizes[2] / N); // 10240
    const int chunk = N / NCHUNK;                      // 2500

    float* out   = (float*)d_out;
    float* out_w = out;
    float* out_v = out + (size_t)B * TOPK;

    char* wsb = (char*)d_ws;
    size_t off = 0;
    float* scores = (float*)(wsb + off); off += (size_t)B * N * sizeof(float);
    unsigned short* qh = (unsigned short*)(wsb + off); off += (size_t)B * DKD * 2;
    float* pm = (float*)(wsb + off); off += (size_t)B * NCHUNK * sizeof(float);
    float* ps = (float*)(wsb + off); off += (size_t)B * NCHUNK * sizeof(float);
    float* cv = (float*)(wsb + off); off += (size_t)B * NCHUNK * TOPK * sizeof(float);
    int*   ci = (int*)(wsb + off);   off += (size_t)B * NCHUNK * TOPK * sizeof(int);
    int*   tidx = (int*)(wsb + off); off += (size_t)B * TOPK * sizeof(int);

    qsplit_kernel<<<B, 128, 0, stream>>>(q, qh);
    scores_mfma_kernel<<<(N + 63) / 64, 256, 0, stream>>>(keys, qh, scores, N);
    part_kernel<<<B * NCHUNK, 256, 0, stream>>>(scores, pm, ps, cv, ci, N, chunk);
    final_kernel<<<B, 64, 0, stream>>>(q, keys, pm, ps, cv, ci, out_w, tidx);
    gather_kernel<<<B * TOPK * 4, 256, 0, stream>>>(values, tidx, out_v, LDV);
}